// Round 1
// baseline (30.371 us; speedup 1.0000x reference)
//
#include <hip/hip_runtime.h>
#include <math.h>

#define KFEAT 32768
#define GRID_N 33              // 33x33 grid, step = 1/32 of domain
#define NPTS (GRID_N * GRID_N) // 1089
#define PTS_PER_BLOCK 4

// ---------------------------------------------------------------------------
// Kernel 1: evaluate f on the 33x33 grid.
// f(x,y) = sum_k w_k * cos(ax_k * x + ay_k * y + phi_k)
// Each block handles 4 consecutive grid points; 256 threads stride over K.
// ---------------------------------------------------------------------------
__global__ __launch_bounds__(256) void eval_grid_kernel(
    const float* __restrict__ w, const float* __restrict__ ax,
    const float* __restrict__ ay, const float* __restrict__ phi,
    const float* __restrict__ xa_p, const float* __restrict__ xb_p,
    const float* __restrict__ ya_p, const float* __restrict__ yb_p,
    float* __restrict__ F) {
  const int tid = threadIdx.x;
  const float xa = xa_p[0], xb = xb_p[0];
  const float ya = ya_p[0], yb = yb_p[0];
  const float sx = (xb - xa) * (1.0f / 32.0f);
  const float sy = (yb - ya) * (1.0f / 32.0f);

  const int p0 = blockIdx.x * PTS_PER_BLOCK;
  float x[PTS_PER_BLOCK], y[PTS_PER_BLOCK];
#pragma unroll
  for (int j = 0; j < PTS_PER_BLOCK; ++j) {
    int p = min(p0 + j, NPTS - 1);  // clamp; duplicate work, write guarded
    int gx = p % GRID_N;
    int gy = p / GRID_N;
    x[j] = fmaf((float)gx, sx, xa);
    y[j] = fmaf((float)gy, sy, ya);
  }

  float acc[PTS_PER_BLOCK] = {0.0f, 0.0f, 0.0f, 0.0f};
  for (int k = tid; k < KFEAT; k += 256) {
    const float A = ax[k];
    const float B = ay[k];
    const float P = phi[k];
    const float W = w[k];
#pragma unroll
    for (int j = 0; j < PTS_PER_BLOCK; ++j) {
      float th = fmaf(A, x[j], fmaf(B, y[j], P));
      acc[j] = fmaf(W, __cosf(th), acc[j]);
    }
  }

  // Reduce each of the 4 accumulators across the 256-thread block.
  __shared__ float red[4][PTS_PER_BLOCK];  // [wave][point]
#pragma unroll
  for (int j = 0; j < PTS_PER_BLOCK; ++j) {
    float v = acc[j];
#pragma unroll
    for (int off = 32; off > 0; off >>= 1) v += __shfl_down(v, off, 64);
    if ((tid & 63) == 0) red[tid >> 6][j] = v;
  }
  __syncthreads();
  if (tid < PTS_PER_BLOCK) {
    const int j = tid;
    float v = red[0][j] + red[1][j] + red[2][j] + red[3][j];
    int p = p0 + j;
    if (p < NPTS) F[p] = v;
  }
}

// ---------------------------------------------------------------------------
// Kernel 2: Simpson cells at depths 0..4 + adaptive tree combine.
// Cell index uses the reference's interleaved quadrant order: the base-4
// digits of the index (MSB = depth 1) are quadrants q in {0:LL,1:LR,2:UL,3:UR};
// ix = even bits of index compacted, iy = odd bits compacted (Morton).
// ---------------------------------------------------------------------------
__device__ __forceinline__ int compact_bits(int v, int shift) {
  int r = (v >> shift) & 1;
  r |= ((v >> (shift + 2)) & 1) << 1;
  r |= ((v >> (shift + 4)) & 1) << 2;
  r |= ((v >> (shift + 6)) & 1) << 3;
  return r;
}

__device__ __forceinline__ float simpson_cell(const float* __restrict__ F,
                                              int d, int cell, float hx,
                                              float hy) {
  const int ix = compact_bits(cell, 0);
  const int iy = compact_bits(cell, 1);
  const int s = 5 - d;        // log2 of cell size in grid units
  const int h = 1 << (s - 1); // half-cell in grid units
  const int gx0 = ix << s, gx1 = gx0 + h, gx2 = gx0 + 2 * h;
  const int gy0 = iy << s, gy1 = gy0 + h, gy2 = gy0 + 2 * h;
  // point order: 0:(xl,yl) 1:(mx,yl) 2:(xr,yl) 3:(xl,my) 4:(xr,my)
  //              5:(xl,yr) 6:(mx,yr) 7:(xr,yr)   (center skipped, coeff 0)
  const float f0 = F[gy0 * GRID_N + gx0];
  const float f1 = F[gy0 * GRID_N + gx1];
  const float f2 = F[gy0 * GRID_N + gx2];
  const float f3 = F[gy1 * GRID_N + gx0];
  const float f4 = F[gy1 * GRID_N + gx2];
  const float f5 = F[gy2 * GRID_N + gx0];
  const float f6 = F[gy2 * GRID_N + gx1];
  const float f7 = F[gy2 * GRID_N + gx2];
  return hx * hy * (1.0f / 12.0f) *
         (-(f0 + f2 + f5 + f7) + 4.0f * (f1 + f3 + f4 + f6));
}

__global__ __launch_bounds__(256) void combine_kernel(
    const float* __restrict__ F, const float* __restrict__ xa_p,
    const float* __restrict__ xb_p, const float* __restrict__ ya_p,
    const float* __restrict__ yb_p, const float* __restrict__ eps_p,
    float* __restrict__ out) {
  __shared__ float S4[256], S3[64], S2[16], S1[4], S0[1];
  __shared__ float val3[64], val2[16], val1[4];
  const int t = threadIdx.x;
  const float xa = *xa_p, xb = *xb_p, ya = *ya_p, yb = *yb_p, eps = *eps_p;
  const float HX = fabsf(xb - xa), HY = fabsf(yb - ya);

  // --- Simpson estimates at every depth ---
  S4[t] = simpson_cell(F, 4, t, HX * 0.0625f, HY * 0.0625f);
  if (t < 64) {
    S3[t] = simpson_cell(F, 3, t, HX * 0.125f, HY * 0.125f);
  } else if (t < 80) {
    S2[t - 64] = simpson_cell(F, 2, t - 64, HX * 0.25f, HY * 0.25f);
  } else if (t < 84) {
    S1[t - 80] = simpson_cell(F, 1, t - 80, HX * 0.5f, HY * 0.5f);
  } else if (t == 84) {
    S0[0] = simpson_cell(F, 0, 0, HX, HY);
  }
  __syncthreads();

  // --- d = 3 (MAX_DEPTH-1): truncate -> corrected unconditionally ---
  if (t < 64) {
    float sumq = ((S4[4 * t] + S4[4 * t + 1]) + S4[4 * t + 2]) + S4[4 * t + 3];
    // reference bug reproduced: quadrant 3 'whole' is quadrant 0's S
    float whole = ((t & 3) == 3) ? S3[t & ~3] : S3[t];
    float delta = sumq - whole;
    val3[t] = sumq + delta * (1.0f / 15.0f);
  }
  __syncthreads();

  // --- d = 2 ---
  if (t < 16) {
    float sumq = ((S3[4 * t] + S3[4 * t + 1]) + S3[4 * t + 2]) + S3[4 * t + 3];
    float whole = ((t & 3) == 3) ? S2[t & ~3] : S2[t];
    float delta = sumq - whole;
    float corrected = sumq + delta * (1.0f / 15.0f);
    float child =
        ((val3[4 * t] + val3[4 * t + 1]) + val3[4 * t + 2]) + val3[4 * t + 3];
    float eps_d = eps * (1.0f / 16.0f);  // eps / 4^2
    val2[t] = (fabsf(delta) <= 15.0f * eps_d) ? corrected : child;
  }
  __syncthreads();

  // --- d = 1 ---
  if (t < 4) {
    float sumq = ((S2[4 * t] + S2[4 * t + 1]) + S2[4 * t + 2]) + S2[4 * t + 3];
    float whole = ((t & 3) == 3) ? S1[t & ~3] : S1[t];
    float delta = sumq - whole;
    float corrected = sumq + delta * (1.0f / 15.0f);
    float child =
        ((val2[4 * t] + val2[4 * t + 1]) + val2[4 * t + 2]) + val2[4 * t + 3];
    float eps_d = eps * 0.25f;  // eps / 4^1
    val1[t] = (fabsf(delta) <= 15.0f * eps_d) ? corrected : child;
  }
  __syncthreads();

  // --- d = 0 ---
  if (t == 0) {
    float sumq = ((S1[0] + S1[1]) + S1[2]) + S1[3];
    float delta = sumq - S0[0];
    float corrected = sumq + delta * (1.0f / 15.0f);
    float child = ((val1[0] + val1[1]) + val1[2]) + val1[3];
    out[0] = (fabsf(delta) <= 15.0f * eps) ? corrected : child;
  }
}

extern "C" void kernel_launch(void* const* d_in, const int* in_sizes, int n_in,
                              void* d_out, int out_size, void* d_ws,
                              size_t ws_size, hipStream_t stream) {
  // input order: xa, xb, ya, yb, eps, w, ax, ay, phi
  const float* xa = (const float*)d_in[0];
  const float* xb = (const float*)d_in[1];
  const float* ya = (const float*)d_in[2];
  const float* yb = (const float*)d_in[3];
  const float* eps = (const float*)d_in[4];
  const float* w = (const float*)d_in[5];
  const float* ax = (const float*)d_in[6];
  const float* ay = (const float*)d_in[7];
  const float* phi = (const float*)d_in[8];
  float* out = (float*)d_out;
  float* F = (float*)d_ws;  // 1089 floats

  const int nblocks = (NPTS + PTS_PER_BLOCK - 1) / PTS_PER_BLOCK;  // 273
  eval_grid_kernel<<<nblocks, 256, 0, stream>>>(w, ax, ay, phi, xa, xb, ya, yb,
                                                F);
  combine_kernel<<<1, 256, 0, stream>>>(F, xa, xb, ya, yb, eps, out);
}

// Round 2
// 26.236 us; speedup vs baseline: 1.1576x; 1.1576x over previous
//
#include <hip/hip_runtime.h>
#include <math.h>

#define KFEAT 32768
#define GRID_N 33              // 33x33 grid, step = 1/32 of domain
#define NPTS (GRID_N * GRID_N) // 1089
#define PTS_PER_BLOCK 8
#define PBLOCKS ((NPTS + PTS_PER_BLOCK - 1) / PTS_PER_BLOCK)  // 137
#define SPLITK 8

// ---------------------------------------------------------------------------
// Kernel 1: evaluate f on the 33x33 grid, split-K partials.
// f(x,y) = sum_k w_k * cos(ax_k * x + ay_k * y + phi_k)
// grid = (137 point-blocks, nsplit K-splits); 256 threads stride over K/4
// float4 elements. Each block writes 8 partial sums to Fpart[split][point].
// ---------------------------------------------------------------------------
__global__ __launch_bounds__(256) void eval_grid_kernel(
    const float4* __restrict__ w4, const float4* __restrict__ ax4,
    const float4* __restrict__ ay4, const float4* __restrict__ phi4,
    const float* __restrict__ xa_p, const float* __restrict__ xb_p,
    const float* __restrict__ ya_p, const float* __restrict__ yb_p,
    float* __restrict__ Fpart, int nsplit) {
  const int tid = threadIdx.x;
  const int pblk = blockIdx.x;
  const int split = blockIdx.y;
  const float xa = xa_p[0], xb = xb_p[0];
  const float ya = ya_p[0], yb = yb_p[0];
  const float sx = (xb - xa) * (1.0f / 32.0f);
  const float sy = (yb - ya) * (1.0f / 32.0f);

  const int p0 = pblk * PTS_PER_BLOCK;
  float x[PTS_PER_BLOCK], y[PTS_PER_BLOCK];
#pragma unroll
  for (int j = 0; j < PTS_PER_BLOCK; ++j) {
    int p = min(p0 + j, NPTS - 1);  // clamp; duplicate work, write guarded
    int gx = p % GRID_N;
    int gy = p / GRID_N;
    x[j] = fmaf((float)gx, sx, xa);
    y[j] = fmaf((float)gy, sy, ya);
  }

  float acc[PTS_PER_BLOCK];
#pragma unroll
  for (int j = 0; j < PTS_PER_BLOCK; ++j) acc[j] = 0.0f;

  const int k4_per_split = (KFEAT / 4) / nsplit;
  const int base = split * k4_per_split;
  for (int i = tid; i < k4_per_split; i += 256) {
    const float4 A = ax4[base + i];
    const float4 B = ay4[base + i];
    const float4 P = phi4[base + i];
    const float4 W = w4[base + i];
#pragma unroll
    for (int j = 0; j < PTS_PER_BLOCK; ++j) {
      float t0 = fmaf(A.x, x[j], fmaf(B.x, y[j], P.x));
      float t1 = fmaf(A.y, x[j], fmaf(B.y, y[j], P.y));
      float t2 = fmaf(A.z, x[j], fmaf(B.z, y[j], P.z));
      float t3 = fmaf(A.w, x[j], fmaf(B.w, y[j], P.w));
      float s = fmaf(W.x, __cosf(t0), fmaf(W.y, __cosf(t1),
                fmaf(W.z, __cosf(t2), W.w * __cosf(t3))));
      acc[j] += s;
    }
  }

  // Reduce each of the 8 accumulators across the 256-thread block.
  __shared__ float red[4][PTS_PER_BLOCK];  // [wave][point]
#pragma unroll
  for (int j = 0; j < PTS_PER_BLOCK; ++j) {
    float v = acc[j];
#pragma unroll
    for (int off = 32; off > 0; off >>= 1) v += __shfl_down(v, off, 64);
    if ((tid & 63) == 0) red[tid >> 6][j] = v;
  }
  __syncthreads();
  if (tid < PTS_PER_BLOCK) {
    const int j = tid;
    float v = red[0][j] + red[1][j] + red[2][j] + red[3][j];
    int p = p0 + j;
    if (p < NPTS) Fpart[split * NPTS + p] = v;
  }
}

// ---------------------------------------------------------------------------
// Kernel 2: sum split-K partials into LDS, then Simpson cells at depths 0..4
// + adaptive tree combine. Cell index uses the reference's interleaved
// quadrant order (base-4 digits, MSB = depth 1): ix = even bits compacted,
// iy = odd bits compacted (Morton).
// ---------------------------------------------------------------------------
__device__ __forceinline__ int compact_bits(int v, int shift) {
  int r = (v >> shift) & 1;
  r |= ((v >> (shift + 2)) & 1) << 1;
  r |= ((v >> (shift + 4)) & 1) << 2;
  r |= ((v >> (shift + 6)) & 1) << 3;
  return r;
}

__device__ __forceinline__ float simpson_cell(const float* __restrict__ F,
                                              int d, int cell, float hx,
                                              float hy) {
  const int ix = compact_bits(cell, 0);
  const int iy = compact_bits(cell, 1);
  const int s = 5 - d;        // log2 of cell size in grid units
  const int h = 1 << (s - 1); // half-cell in grid units
  const int gx0 = ix << s, gx1 = gx0 + h, gx2 = gx0 + 2 * h;
  const int gy0 = iy << s, gy1 = gy0 + h, gy2 = gy0 + 2 * h;
  // point order: 0:(xl,yl) 1:(mx,yl) 2:(xr,yl) 3:(xl,my) 4:(xr,my)
  //              5:(xl,yr) 6:(mx,yr) 7:(xr,yr)   (center skipped, coeff 0)
  const float f0 = F[gy0 * GRID_N + gx0];
  const float f1 = F[gy0 * GRID_N + gx1];
  const float f2 = F[gy0 * GRID_N + gx2];
  const float f3 = F[gy1 * GRID_N + gx0];
  const float f4 = F[gy1 * GRID_N + gx2];
  const float f5 = F[gy2 * GRID_N + gx0];
  const float f6 = F[gy2 * GRID_N + gx1];
  const float f7 = F[gy2 * GRID_N + gx2];
  return hx * hy * (1.0f / 12.0f) *
         (-(f0 + f2 + f5 + f7) + 4.0f * (f1 + f3 + f4 + f6));
}

__global__ __launch_bounds__(256) void combine_kernel(
    const float* __restrict__ Fpart, const float* __restrict__ xa_p,
    const float* __restrict__ xb_p, const float* __restrict__ ya_p,
    const float* __restrict__ yb_p, const float* __restrict__ eps_p,
    float* __restrict__ out, int nsplit) {
  __shared__ float Fs[NPTS];
  __shared__ float S4[256], S3[64], S2[16], S1[4], S0[1];
  __shared__ float val3[64], val2[16], val1[4];
  const int t = threadIdx.x;
  const float xa = *xa_p, xb = *xb_p, ya = *ya_p, yb = *yb_p, eps = *eps_p;
  const float HX = fabsf(xb - xa), HY = fabsf(yb - ya);

  // --- sum split-K partials into LDS ---
  for (int p = t; p < NPTS; p += 256) {
    float v = 0.0f;
    for (int s = 0; s < nsplit; ++s) v += Fpart[s * NPTS + p];
    Fs[p] = v;
  }
  __syncthreads();

  // --- Simpson estimates at every depth ---
  S4[t] = simpson_cell(Fs, 4, t, HX * 0.0625f, HY * 0.0625f);
  if (t < 64) {
    S3[t] = simpson_cell(Fs, 3, t, HX * 0.125f, HY * 0.125f);
  } else if (t < 80) {
    S2[t - 64] = simpson_cell(Fs, 2, t - 64, HX * 0.25f, HY * 0.25f);
  } else if (t < 84) {
    S1[t - 80] = simpson_cell(Fs, 1, t - 80, HX * 0.5f, HY * 0.5f);
  } else if (t == 84) {
    S0[0] = simpson_cell(Fs, 0, 0, HX, HY);
  }
  __syncthreads();

  // --- d = 3 (MAX_DEPTH-1): truncate -> corrected unconditionally ---
  if (t < 64) {
    float sumq = ((S4[4 * t] + S4[4 * t + 1]) + S4[4 * t + 2]) + S4[4 * t + 3];
    // reference bug reproduced: quadrant 3 'whole' is quadrant 0's S
    float whole = ((t & 3) == 3) ? S3[t & ~3] : S3[t];
    float delta = sumq - whole;
    val3[t] = sumq + delta * (1.0f / 15.0f);
  }
  __syncthreads();

  // --- d = 2 ---
  if (t < 16) {
    float sumq = ((S3[4 * t] + S3[4 * t + 1]) + S3[4 * t + 2]) + S3[4 * t + 3];
    float whole = ((t & 3) == 3) ? S2[t & ~3] : S2[t];
    float delta = sumq - whole;
    float corrected = sumq + delta * (1.0f / 15.0f);
    float child =
        ((val3[4 * t] + val3[4 * t + 1]) + val3[4 * t + 2]) + val3[4 * t + 3];
    float eps_d = eps * (1.0f / 16.0f);  // eps / 4^2
    val2[t] = (fabsf(delta) <= 15.0f * eps_d) ? corrected : child;
  }
  __syncthreads();

  // --- d = 1 ---
  if (t < 4) {
    float sumq = ((S2[4 * t] + S2[4 * t + 1]) + S2[4 * t + 2]) + S2[4 * t + 3];
    float whole = ((t & 3) == 3) ? S1[t & ~3] : S1[t];
    float delta = sumq - whole;
    float corrected = sumq + delta * (1.0f / 15.0f);
    float child =
        ((val2[4 * t] + val2[4 * t + 1]) + val2[4 * t + 2]) + val2[4 * t + 3];
    float eps_d = eps * 0.25f;  // eps / 4^1
    val1[t] = (fabsf(delta) <= 15.0f * eps_d) ? corrected : child;
  }
  __syncthreads();

  // --- d = 0 ---
  if (t == 0) {
    float sumq = ((S1[0] + S1[1]) + S1[2]) + S1[3];
    float delta = sumq - S0[0];
    float corrected = sumq + delta * (1.0f / 15.0f);
    float child = ((val1[0] + val1[1]) + val1[2]) + val1[3];
    out[0] = (fabsf(delta) <= 15.0f * eps) ? corrected : child;
  }
}

extern "C" void kernel_launch(void* const* d_in, const int* in_sizes, int n_in,
                              void* d_out, int out_size, void* d_ws,
                              size_t ws_size, hipStream_t stream) {
  // input order: xa, xb, ya, yb, eps, w, ax, ay, phi
  const float* xa = (const float*)d_in[0];
  const float* xb = (const float*)d_in[1];
  const float* ya = (const float*)d_in[2];
  const float* yb = (const float*)d_in[3];
  const float* eps = (const float*)d_in[4];
  const float4* w4 = (const float4*)d_in[5];
  const float4* ax4 = (const float4*)d_in[6];
  const float4* ay4 = (const float4*)d_in[7];
  const float4* phi4 = (const float4*)d_in[8];
  float* out = (float*)d_out;
  float* Fpart = (float*)d_ws;

  const int nsplit =
      (ws_size >= (size_t)SPLITK * NPTS * sizeof(float)) ? SPLITK : 1;

  dim3 grid(PBLOCKS, nsplit);
  eval_grid_kernel<<<grid, 256, 0, stream>>>(w4, ax4, ay4, phi4, xa, xb, ya,
                                             yb, Fpart, nsplit);
  combine_kernel<<<1, 256, 0, stream>>>(Fpart, xa, xb, ya, yb, eps, out,
                                        nsplit);
}